// Round 1
// baseline (179.024 us; speedup 1.0000x reference)
//
#include <hip/hip_runtime.h>

// Problem constants (MultiAttention_61340722921598)
#define BATCH 2
#define SEQ   2048
#define DMODEL 1024
#define NHEADS 16
#define HDIM   64
#define WINDOW 128
#define ROWS  (BATCH * SEQ)          // 4096

typedef __bf16 bf16x8 __attribute__((ext_vector_type(8)));
typedef __bf16 bf16x4 __attribute__((ext_vector_type(4)));
typedef float  f32x4  __attribute__((ext_vector_type(4)));

// async global->LDS, 16B per lane; LDS dest = wave-uniform base + lane*16
__device__ __forceinline__ void async_load16(const __bf16* g, __bf16* l) {
    __builtin_amdgcn_global_load_lds(
        (const __attribute__((address_space(1))) unsigned int*)g,
        (__attribute__((address_space(3))) unsigned int*)l, 16, 0, 0);
}

// ---------------------------------------------------------------------------
// fp32 -> bf16 conversion of X and the 4 weights; tail range computes the
// RoPE cos/sin table (exact libm sincosf, matching the fp32 reference).
// ---------------------------------------------------------------------------
__global__ __launch_bounds__(256) void convert_bf16(
    const float* __restrict__ X,
    const float* __restrict__ Wq, const float* __restrict__ Wk,
    const float* __restrict__ Wv, const float* __restrict__ Wo,
    __bf16* __restrict__ Xbf, __bf16* __restrict__ Wbf,
    float* __restrict__ ct, float* __restrict__ st)
{
    const int XN = ROWS * DMODEL / 4;     // 1,048,576 groups
    const int WN = DMODEL * DMODEL / 4;   // 262,144 per W
    const int TOT = XN + 4 * WN;          // 2,097,152
    int idx = blockIdx.x * blockDim.x + threadIdx.x;

    if (idx < TOT) {
        const float* src;
        __bf16* dst;
        if (idx < XN) {
            src = X + (size_t)idx * 4;
            dst = Xbf + (size_t)idx * 4;
        } else {
            int rel = idx - XN;
            int w = rel / WN;
            int off = rel - w * WN;
            const float* Wp = (w == 0) ? Wq : (w == 1) ? Wk : (w == 2) ? Wv : Wo;
            src = Wp + (size_t)off * 4;
            dst = Wbf + (size_t)rel * 4;
        }
        float4 v = *(const float4*)src;
        bf16x4 o;
        o[0] = (__bf16)v.x; o[1] = (__bf16)v.y; o[2] = (__bf16)v.z; o[3] = (__bf16)v.w;
        *(bf16x4*)dst = o;
    } else if (idx < TOT + SEQ * 32) {
        int k = idx - TOT;
        int t = k >> 5, d = k & 31;
        float ang = (float)t * expf(-(float)d * 0.28782313662425572f); // ln(1e4)/32
        float s, c;
        sincosf(ang, &s, &c);
        ct[k] = c; st[k] = s;
    }
}

// ---------------------------------------------------------------------------
// bf16 MFMA GEMM: C[m][n] = sum_k A[m][k] * B[n][k]. m97 structure: BK=32,
// single-buffer LDS (16 KB for 128x128 -> ~5 blocks/CU; the previous BK=128
// variant's 64 KB LDS reproduced the m132 regression at 2 blocks/CU).
// XOR chunk swizzle (r4-verified): LDS row r slot s holds global chunk
// s^((r>>1)&3) via source-address permutation; <=2-way conflicts (free).
// 256 threads = 4 waves.
//   TN=128 -> 2x2 wave layout: wave = 64x64 outputs, 8 ds_read_b128 per
//             16 MFMA per K-step (0.5/MFMA, m97 ratio).
//   TN=64  -> 4x1 wave layout (kept for generality; unused this round).
// Epilogue modes: 0=Q (RoPE+0.125, bf16), 1=K (RoPE, bf16), 2=V (bf16),
// 3=fp32+bias. wcol is a multiple of 64 in both layouts -> RoPE pairs
// (d, d+32) stay in one wave as (acc[i][j], acc[i][j+2]), d=j*16+(lane&15).
// A/B-frag: elem[row=lane&15][k=(lane>>4)*8+j]; C/D: col=lane&15,
// row=(lane>>4)*4+reg (verified m89, rounds 2-8).
// ---------------------------------------------------------------------------
template<int TM, int TN>
__device__ __forceinline__ void gemm_mfma_body(
    const __bf16* __restrict__ A, const __bf16* __restrict__ B,
    void* __restrict__ Cout, const float* __restrict__ bias,
    const float* __restrict__ ct, const float* __restrict__ st,
    int mode, int N, int K, int m0, int n0)
{
    constexpr bool SQ = (TN == 128);          // 2x2 wave layout
    constexpr int NI = SQ ? 4 : (TM / 64);    // 16-row i-tiles per wave
    constexpr int NAC = TM / 64;              // A staging calls per wave
    constexpr int NBC = TN / 64;              // B staging calls per wave
    __shared__ __bf16 As[TM * 32];
    __shared__ __bf16 Bs[TN * 32];

    const int tid  = threadIdx.x;
    const int lane = tid & 63;
    const int wv   = tid >> 6;
    const int wrow = SQ ? (wv >> 1) * 64 : wv * (TM / 4);
    const int wcol = SQ ? (wv & 1) * 64 : 0;

    // staging map (per 16-row call): lane -> row lane>>2, slot lane&3,
    // source chunk (lane&3)^((lane>>3)&3); row-base-invariant (base % 16 == 0)
    const int srow = lane >> 2;
    const int schk = (lane & 3) ^ ((lane >> 3) & 3);
    const int arbase = wv * (TM / 4);
    const int brbase = wv * (TN / 4);

    const __bf16* gA0 = A + (size_t)(m0 + arbase + srow) * K + 8 * schk;
    const __bf16* gA1 = gA0 + (size_t)16 * K;
    const __bf16* gB0 = B + (size_t)(n0 + brbase + srow) * K + 8 * schk;
    const __bf16* gB1 = gB0 + (size_t)16 * K;

    // fragment read map: row frow, global chunk lane>>4 at swizzled slot
    const int frow = lane & 15;
    const int fsw  = 8 * ((lane >> 4) ^ ((frow >> 1) & 3));

    f32x4 acc[NI][4];
#pragma unroll
    for (int i = 0; i < NI; ++i)
#pragma unroll
        for (int j = 0; j < 4; ++j) {
            acc[i][j][0] = 0.f; acc[i][j][1] = 0.f;
            acc[i][j][2] = 0.f; acc[i][j][3] = 0.f;
        }

    for (int k0 = 0; k0 < K; k0 += 32) {
        __syncthreads();                 // prior iter's LDS reads complete
        async_load16(gA0 + k0, As + arbase * 32);
        if (NAC == 2)
            async_load16(gA1 + k0, As + (arbase + 16) * 32);
        async_load16(gB0 + k0, Bs + brbase * 32);
        if (NBC == 2)
            async_load16(gB1 + k0, Bs + (brbase + 16) * 32);
        __syncthreads();                 // drains vmcnt: staging visible

        bf16x8 afr[NI], bfr[4];
#pragma unroll
        for (int i = 0; i < NI; ++i)
            afr[i] = *(const bf16x8*)(As + (wrow + 16 * i + frow) * 32 + fsw);
#pragma unroll
        for (int j = 0; j < 4; ++j)
            bfr[j] = *(const bf16x8*)(Bs + (wcol + 16 * j + frow) * 32 + fsw);
#pragma unroll
        for (int i = 0; i < NI; ++i)
#pragma unroll
            for (int j = 0; j < 4; ++j)
                acc[i][j] = __builtin_amdgcn_mfma_f32_16x16x32_bf16(
                    afr[i], bfr[j], acc[i][j], 0, 0, 0);
    }

#pragma unroll
    for (int i = 0; i < NI; ++i) {
#pragma unroll
        for (int r = 0; r < 4; ++r) {
            int row = m0 + wrow + i * 16 + (lane >> 4) * 4 + r;
            if (mode <= 1) {
                // RoPE: pairs (d, d+32) in (acc[i][j], acc[i][j+2]), d=j*16+(lane&15)<32
                int t = row & (SEQ - 1);
#pragma unroll
                for (int j = 0; j < 2; ++j) {
                    int dd = j * 16 + (lane & 15);
                    float c = ct[t * 32 + dd];
                    float s = st[t * 32 + dd];
                    float v0 = acc[i][j][r], v1 = acc[i][j + 2][r];
                    float n0v = v0 * c - v1 * s;
                    float n1v = v1 * c + v0 * s;
                    if (mode == 0) { n0v *= 0.125f; n1v *= 0.125f; }
                    acc[i][j][r] = n0v; acc[i][j + 2][r] = n1v;
                }
            }
#pragma unroll
            for (int j = 0; j < 4; ++j) {
                int col = n0 + wcol + j * 16 + (lane & 15);
                float v = acc[i][j][r];
                if (mode == 3)
                    ((float*)Cout)[(size_t)row * N + col] = v + bias[col];
                else
                    ((__bf16*)Cout)[(size_t)row * N + col] = (__bf16)v;
            }
        }
    }
}

// XCD-locality swizzle (verified r7/r8): id = bx + GX*by, XCD = id&7
// (round-robin dispatch). Each XCD gets GY/8 y-stripes so the GX blocks
// sharing one A-row-tile sit on ONE XCD; z-stride GX*GY % 8 == 0 keeps the
// same (x,y) on the same XCD across z.
template<int GX, int GY>
__device__ __forceinline__ void xcd_swizzle(int& xb, int& yb)
{
    int id = blockIdx.x + GX * blockIdx.y;
    int q  = id & 7;
    int s  = id >> 3;
    xb = s % GX;
    yb = (GY / 8) * q + s / GX;
}

__global__ __launch_bounds__(256) void gemm_qkv_bf(
    const __bf16* __restrict__ X, const __bf16* __restrict__ Wbf,
    __bf16* __restrict__ Qb, __bf16* __restrict__ Kb, __bf16* __restrict__ Vb,
    const float* __restrict__ ct, const float* __restrict__ st)
{
    const int z = blockIdx.z;
    const __bf16* W = Wbf + (size_t)z * (DMODEL * DMODEL);
    __bf16* C = (z == 0) ? Qb : (z == 1) ? Kb : Vb;
    int xb, yb;
    xcd_swizzle<8, 32>(xb, yb);
    gemm_mfma_body<128, 128>(X, W, C, nullptr, ct, st, z, DMODEL, DMODEL,
                             yb * 128, xb * 128);
}

__global__ __launch_bounds__(256) void gemm_out_bf(
    const __bf16* __restrict__ Abf, const __bf16* __restrict__ Wo,
    const float* __restrict__ bias, float* __restrict__ out)
{
    int xb, yb;
    xcd_swizzle<8, 32>(xb, yb);
    gemm_mfma_body<128, 128>(Abf, Wo, out, bias, nullptr, nullptr, 3,
                             DMODEL, DMODEL, yb * 128, xb * 128);
}

// ---------------------------------------------------------------------------
// MFMA sliding-window attention (verified rounds 3-8). One 256-thread block
// per (b, h, 64 q-rows); wave w owns q-rows 16w..16w+15.
// ---------------------------------------------------------------------------
#define QTILE 64
#define KPAD  72    // Ks row (bf16): 36 words/row -> 8 distinct bank offsets
#define VPAD  216   // Vt row: 108 words -> 8 distinct offsets
#define PPAD  168   // Ps row: 84 words -> 8 distinct offsets

__global__ __launch_bounds__(256) void attn_mfma(
    const __bf16* __restrict__ Qb, const __bf16* __restrict__ Kb,
    const __bf16* __restrict__ Vb, __bf16* __restrict__ Abf)
{
    __shared__ __bf16 KsPs[192 * KPAD];  // 27648 B; Ks, then reused as Ps
    __shared__ __bf16 Vt[64 * VPAD];     // 27648 B  (total 55296 B)

    const int tid  = threadIdx.x;
    const int lane = tid & 63;
    const int wv   = tid >> 6;
    const int q0   = blockIdx.x * QTILE;
    const int h    = blockIdx.y;
    const int b    = blockIdx.z;
    const int jbase = q0 - 128;
    const size_t hoff = (size_t)h * HDIM;
    const int nloc  = lane & 15;
    const int mbase = (lane >> 4) * 4;
    const int fk    = (lane >> 4) * 8;

    const __bf16* Kg = Kb + (size_t)(b * SEQ) * DMODEL + hoff;
    const __bf16* Vg = Vb + (size_t)(b * SEQ) * DMODEL + hoff;

    // ---- stage Ks (natural) + Vt (transposed)
#pragma unroll
    for (int it = 0; it < 6; ++it) {
        int idx = tid + it * 256;          // 0..1535
        int jt = idx >> 3;                 // 0..191
        int dq = (idx & 7) * 8;
        int jg = jbase + jt;
        int jc = jg < 0 ? 0 : jg;          // clamp; masked via p=0 later
        bf16x8 kv = *(const bf16x8*)(Kg + (size_t)jc * DMODEL + dq);
        bf16x8 vv = *(const bf16x8*)(Vg + (size_t)jc * DMODEL + dq);
        *(bf16x8*)(KsPs + jt * KPAD + dq) = kv;
#pragma unroll
        for (int e = 0; e < 8; ++e) Vt[(dq + e) * VPAD + jt] = vv[e];
    }
    // zero Vt cols [192,208) (read by PV k-steps; must not be garbage)
#pragma unroll
    for (int it = 0; it < 4; ++it) {
        int idx = tid + it * 256;          // 0..1023
        int d = idx >> 4, c = idx & 15;
        Vt[d * VPAD + 192 + c] = (__bf16)0.0f;
    }
    __syncthreads();

    // ---- Q A-frags direct from global
    const __bf16* Qg = Qb + (size_t)(b * SEQ + q0 + 16 * wv + nloc) * DMODEL + hoff + fk;
    bf16x8 qfr0 = *(const bf16x8*)(Qg);
    bf16x8 qfr1 = *(const bf16x8*)(Qg + 32);

    // ---- S = Q K^T over 9 column tiles
    f32x4 s[9];
#pragma unroll
    for (int c = 0; c < 9; ++c) {
        const __bf16* kp = KsPs + (size_t)(16 * (wv + c) + nloc) * KPAD + fk;
        bf16x8 k0 = *(const bf16x8*)kp;
        bf16x8 k1 = *(const bf16x8*)(kp + 32);
        f32x4 z; z[0] = 0.f; z[1] = 0.f; z[2] = 0.f; z[3] = 0.f;
        z = __builtin_amdgcn_mfma_f32_16x16x32_bf16(qfr0, k0, z, 0, 0, 0);
        z = __builtin_amdgcn_mfma_f32_16x16x32_bf16(qfr1, k1, z, 0, 0, 0);
        s[c] = z;
    }
    __syncthreads();   // all waves done reading Ks; safe to alias with Ps

    // ---- mask + softmax (registers only); write normalized P (bf16)
    float inv_row[4];
#pragma unroll
    for (int r = 0; r < 4; ++r) {
        int rl = 16 * wv + mbase + r;
        float mx = -INFINITY;
#pragma unroll
        for (int c = 0; c < 9; ++c) {
            int jt = 16 * (wv + c) + nloc;
            bool valid = (jt >= rl + 1) && (jt <= rl + 128) && (jbase + jt >= 0);
            float sv = valid ? s[c][r] : -INFINITY;
            s[c][r] = sv;
            mx = fmaxf(mx, sv);
        }
#pragma unroll
        for (int off = 8; off; off >>= 1) mx = fmaxf(mx, __shfl_xor(mx, off));
        float sum = 0.f;
#pragma unroll
        for (int c = 0; c < 9; ++c) {
            float p = __expf(s[c][r] - mx);
            s[c][r] = p;
            sum += p;
        }
#pragma unroll
        for (int off = 8; off; off >>= 1) sum += __shfl_xor(sum, off);
        inv_row[r] = 1.0f / sum;
    }

    __bf16* myP = KsPs + (size_t)wv * 16 * PPAD;
#pragma unroll
    for (int c = 0; c < 9; ++c)
#pragma unroll
        for (int r = 0; r < 4; ++r)
            myP[(mbase + r) * PPAD + 16 * c + nloc] = (__bf16)(s[c][r] * inv_row[r]);
#pragma unroll
    for (int r = 0; r < 4; ++r)       // zero P cols [144,160)
        myP[(mbase + r) * PPAD + 144 + nloc] = (__bf16)0.0f;

    asm volatile("" ::: "memory");
    __builtin_amdgcn_s_waitcnt(0);    // wave-local LDS write->read ordering

    // ---- O = P V  (5 k-steps of 32 keys, 4 d-tiles)
    f32x4 o[4];
#pragma unroll
    for (int j = 0; j < 4; ++j) { o[j][0] = 0.f; o[j][1] = 0.f; o[j][2] = 0.f; o[j][3] = 0.f; }
#pragma unroll
    for (int stp = 0; stp < 5; ++stp) {
        bf16x8 pf = *(const bf16x8*)(myP + nloc * PPAD + 32 * stp + fk);
#pragma unroll
        for (int j = 0; j < 4; ++j) {
            bf16x8 vf = *(const bf16x8*)(Vt + (size_t)(16 * j + nloc) * VPAD
                                         + 16 * wv + 32 * stp + fk);
            o[j] = __builtin_amdgcn_mfma_f32_16x16x32_bf16(pf, vf, o[j], 0, 0, 0);
        }
    }

    // ---- epilogue: C-layout -> global bf16
    __bf16* Og = Abf + (size_t)(b * SEQ + q0 + 16 * wv) * DMODEL + hoff;
#pragma unroll
    for (int j = 0; j < 4; ++j)
#pragma unroll
        for (int r = 0; r < 4; ++r)
            Og[(size_t)(mbase + r) * DMODEL + 16 * j + nloc] = (__bf16)o[j][r];
}

// ---------------------------------------------------------------------------
extern "C" void kernel_launch(void* const* d_in, const int* in_sizes, int n_in,
                              void* d_out, int out_size, void* d_ws, size_t ws_size,
                              hipStream_t stream)
{
    const float* X  = (const float*)d_in[0];
    const float* Wq = (const float*)d_in[1];
    const float* Wk = (const float*)d_in[2];
    const float* Wv = (const float*)d_in[3];
    const float* Wo = (const float*)d_in[4];
    const float* bo = (const float*)d_in[5];
    float* out = (float*)d_out;

    const size_t MB = 1ull << 20;
    __bf16* Xbf = (__bf16*)d_ws;                        // 8 MB; reused as Abf
    __bf16* Wbf = (__bf16*)((char*)d_ws + 8 * MB);      // 8 MB (Wq|Wk|Wv|Wo)
    __bf16* Qb  = (__bf16*)((char*)d_ws + 16 * MB);     // 8 MB
    __bf16* Kb  = (__bf16*)((char*)d_ws + 24 * MB);     // 8 MB
    __bf16* Vb  = (__bf16*)((char*)d_ws + 32 * MB);     // 8 MB
    float*  ctab = (float*)((char*)d_ws + 40 * MB);     // 256 KB
    float*  stab = (float*)((char*)d_ws + 41 * MB);     // 256 KB
    __bf16* Abf = Xbf;   // X dead after QKV projection

    // 1. fp32 -> bf16 conversion + RoPE table (fused)
    {
        int total = (ROWS * DMODEL + 4 * DMODEL * DMODEL) / 4 + SEQ * 32;
        convert_bf16<<<(total + 255) / 256, 256, 0, stream>>>(
            X, Wq, Wk, Wv, Wo, Xbf, Wbf, ctab, stab);
    }
    // 2. QKV projections with fused RoPE (+Q scale), bf16 out; 128x128 tiles,
    //    BK=32 m97 structure (16 KB LDS -> ~5 blocks/CU)
    {
        dim3 grid(DMODEL / 128, ROWS / 128, 3);
        gemm_qkv_bf<<<grid, 256, 0, stream>>>(Xbf, Wbf, Qb, Kb, Vb, ctab, stab);
    }
    // 3. MFMA sliding-window attention -> bf16
    {
        dim3 grid(SEQ / QTILE, NHEADS, BATCH);
        attn_mfma<<<grid, 256, 0, stream>>>(Qb, Kb, Vb, Abf);
    }
    // 4. Output projection + bias (fp32 out); 128x128 tiles
    {
        dim3 grid(DMODEL / 128, ROWS / 128, 1);
        gemm_out_bf<<<grid, 256, 0, stream>>>(Abf, Wbf + 3ull * DMODEL * DMODEL, bo, out);
    }
}

// Round 2
// 164.594 us; speedup vs baseline: 1.0877x; 1.0877x over previous
//
#include <hip/hip_runtime.h>

// Problem constants (MultiAttention_61340722921598)
#define BATCH 2
#define SEQ   2048
#define DMODEL 1024
#define NHEADS 16
#define HDIM   64
#define WINDOW 128
#define ROWS  (BATCH * SEQ)          // 4096

typedef __bf16 bf16x8 __attribute__((ext_vector_type(8)));
typedef __bf16 bf16x4 __attribute__((ext_vector_type(4)));
typedef float  f32x4  __attribute__((ext_vector_type(4)));

// async global->LDS, 16B per lane; LDS dest = wave-uniform base + lane*16
__device__ __forceinline__ void async_load16(const __bf16* g, __bf16* l) {
    __builtin_amdgcn_global_load_lds(
        (const __attribute__((address_space(1))) unsigned int*)g,
        (__attribute__((address_space(3))) unsigned int*)l, 16, 0, 0);
}

// ---------------------------------------------------------------------------
// fp32 -> bf16 conversion of X and the 4 weights; tail range computes the
// RoPE cos/sin table (exact libm sincosf, matching the fp32 reference).
// ---------------------------------------------------------------------------
__global__ __launch_bounds__(256) void convert_bf16(
    const float* __restrict__ X,
    const float* __restrict__ Wq, const float* __restrict__ Wk,
    const float* __restrict__ Wv, const float* __restrict__ Wo,
    __bf16* __restrict__ Xbf, __bf16* __restrict__ Wbf,
    float* __restrict__ ct, float* __restrict__ st)
{
    const int XN = ROWS * DMODEL / 4;     // 1,048,576 groups
    const int WN = DMODEL * DMODEL / 4;   // 262,144 per W
    const int TOT = XN + 4 * WN;          // 2,097,152
    int idx = blockIdx.x * blockDim.x + threadIdx.x;

    if (idx < TOT) {
        const float* src;
        __bf16* dst;
        if (idx < XN) {
            src = X + (size_t)idx * 4;
            dst = Xbf + (size_t)idx * 4;
        } else {
            int rel = idx - XN;
            int w = rel / WN;
            int off = rel - w * WN;
            const float* Wp = (w == 0) ? Wq : (w == 1) ? Wk : (w == 2) ? Wv : Wo;
            src = Wp + (size_t)off * 4;
            dst = Wbf + (size_t)rel * 4;
        }
        float4 v = *(const float4*)src;
        bf16x4 o;
        o[0] = (__bf16)v.x; o[1] = (__bf16)v.y; o[2] = (__bf16)v.z; o[3] = (__bf16)v.w;
        *(bf16x4*)dst = o;
    } else if (idx < TOT + SEQ * 32) {
        int k = idx - TOT;
        int t = k >> 5, d = k & 31;
        float ang = (float)t * expf(-(float)d * 0.28782313662425572f); // ln(1e4)/32
        float s, c;
        sincosf(ang, &s, &c);
        ct[k] = c; st[k] = s;
    }
}

// ---------------------------------------------------------------------------
// QKV projection: 8-phase 256x256x(BK=64) schedule (m201 port, plain HIP).
// Single fused GEMM: A = Xbf [4096x1024], B = Wq|Wk|Wv rows [3072x1024],
// C[m][n] = sum_k A[m][k] B[n][k].  512 threads = 8 waves (2 M x 4 N),
// per-wave output 128x64 (acc[8][4] f32x4).  LDS 128 KB: As/Bs double-
// buffered [2][256][64] bf16, linear row-major with XOR slot swizzle:
// LDS row r, 16B-slot s holds global slot s^(r&7) (inverse-swizzled global
// source feeding linear global_load_lds dest; swizzled ds_read).  Main loop
// uses RAW s_barrier (no vmcnt drain) + one vmcnt(0) per K-tile at phase 3,
// 2-3 phases after the prefetch issue -> near-free (T3+T4).  T5 setprio
// around each 16-MFMA cluster.  Epilogue: RoPE (+0.125 Q scale) as in the
// verified round-0 mapping (wave col-span 64; pairs acc[i][j]/acc[i][j+2]).
// A/B-frag: elem[row=lane&15][k=(lane>>4)*8+j]; C/D: col=lane&15,
// row=(lane>>4)*4+reg (verified m89, rounds 2-8).
// ---------------------------------------------------------------------------
#define RAW_BAR __builtin_amdgcn_s_barrier()
#define LGKM0   asm volatile("s_waitcnt lgkmcnt(0)" ::: "memory")
#define VM0     asm volatile("s_waitcnt vmcnt(0)" ::: "memory")
#define CFENCE  asm volatile("" ::: "memory")
#define MFMA16(a, b, c) __builtin_amdgcn_mfma_f32_16x16x32_bf16(a, b, c, 0, 0, 0)

__global__ __launch_bounds__(512, 2) void gemm_qkv_8ph(
    const __bf16* __restrict__ X, const __bf16* __restrict__ Wbf,
    __bf16* __restrict__ Qb, __bf16* __restrict__ Kb, __bf16* __restrict__ Vb,
    const float* __restrict__ ct, const float* __restrict__ st)
{
    __shared__ __bf16 As[2][256 * 64];   // 64 KB
    __shared__ __bf16 Bs[2][256 * 64];   // 64 KB

    const int tid  = threadIdx.x;
    const int lane = tid & 63;
    const int wv   = tid >> 6;           // 0..7
    const int wr   = wv >> 2;            // 0..1 (M)
    const int wc   = wv & 3;             // 0..3 (N)

    // grid 12x16 = 192 blocks; XCD-chunked swizzle (192 % 8 == 0, bijective):
    // XCD q gets tiles [24q, 24q+24) = 2 full y-stripes -> A-panel L2 reuse x12.
    int id = blockIdx.x + 12 * blockIdx.y;
    int tt = (id & 7) * 24 + (id >> 3);
    const int xb = tt % 12, yb = tt / 12;
    const int m0 = yb * 256;
    const int n0 = xb * 256;             // 0..2816, never crosses a 1024 boundary

    // ---- staging maps: wave wv covers rows [wv*16, wv*16+16) of each half;
    // lane l -> row +(l>>3), slot l&7 in LDS; global slot (l&7)^(l>>3)
    // (inverse of the read-side XOR since row&7 == l>>3).
    const int srow = wv * 16 + (lane >> 3);
    const int schk = 8 * ((lane & 7) ^ (lane >> 3));
    const __bf16* gA = X   + (size_t)(m0 + srow) * DMODEL + schk;
    const __bf16* gB = Wbf + (size_t)(n0 + srow) * DMODEL + schk;
    const int lbase = wv * 16 * 64;      // element offset of wave's stripe, half 0

#define STAGE_A(buf, k0) do {                                          \
    async_load16(gA + (k0),                &As[buf][lbase]);           \
    async_load16(gA + (k0) + 8 * DMODEL,   &As[buf][lbase + 8 * 64]);  \
    async_load16(gA + (k0) + 128 * DMODEL, &As[buf][lbase + 128 * 64]);\
    async_load16(gA + (k0) + 136 * DMODEL, &As[buf][lbase + 136 * 64]);} while (0)
#define STAGE_B(buf, k0) do {                                          \
    async_load16(gB + (k0),                &Bs[buf][lbase]);           \
    async_load16(gB + (k0) + 8 * DMODEL,   &Bs[buf][lbase + 8 * 64]);  \
    async_load16(gB + (k0) + 128 * DMODEL, &Bs[buf][lbase + 128 * 64]);\
    async_load16(gB + (k0) + 136 * DMODEL, &Bs[buf][lbase + 136 * 64]);} while (0)

    // ---- fragment read maps (swizzled slot = desired ^ (row&7), row&7 = frow&7)
    const int frow = lane & 15;
    const int hi   = lane >> 4;
    const int s0   = 8 * (hi ^ (frow & 7));        // k-step 0: slots 0..3
    const int s1   = 8 * ((4 + hi) ^ (frow & 7));  // k-step 1: slots 4..7
    const int aoff = (wr * 128 + frow) * 64;
    const int boff = (wc * 64 + frow) * 64;

    f32x4 acc[8][4];
#pragma unroll
    for (int i = 0; i < 8; ++i)
#pragma unroll
        for (int j = 0; j < 4; ++j) {
            acc[i][j][0] = 0.f; acc[i][j][1] = 0.f;
            acc[i][j][2] = 0.f; acc[i][j][3] = 0.f;
        }

// one phase: [stage] -> 4 A-frag ds_reads -> bar -> lgkm(0) -> 16 MFMA -> [vm] -> bar
#define PHASE(I2, STAGE_STMT, VM_STMT) do {                                  \
    STAGE_STMT;                                                              \
    bf16x8 aA = *(const bf16x8*)&Ac[aoff + (I2) * 1024 + s0];                \
    bf16x8 aB = *(const bf16x8*)&Ac[aoff + (I2) * 1024 + s1];                \
    bf16x8 aC = *(const bf16x8*)&Ac[aoff + (I2) * 1024 + 1024 + s0];         \
    bf16x8 aD = *(const bf16x8*)&Ac[aoff + (I2) * 1024 + 1024 + s1];         \
    CFENCE; RAW_BAR; CFENCE; LGKM0;                                          \
    __builtin_amdgcn_s_setprio(1);                                           \
    acc[I2][0] = MFMA16(aA, bfr[0][0], acc[I2][0]);                          \
    acc[I2][1] = MFMA16(aA, bfr[1][0], acc[I2][1]);                          \
    acc[I2][2] = MFMA16(aA, bfr[2][0], acc[I2][2]);                          \
    acc[I2][3] = MFMA16(aA, bfr[3][0], acc[I2][3]);                          \
    acc[I2][0] = MFMA16(aB, bfr[0][1], acc[I2][0]);                          \
    acc[I2][1] = MFMA16(aB, bfr[1][1], acc[I2][1]);                          \
    acc[I2][2] = MFMA16(aB, bfr[2][1], acc[I2][2]);                          \
    acc[I2][3] = MFMA16(aB, bfr[3][1], acc[I2][3]);                          \
    acc[(I2)+1][0] = MFMA16(aC, bfr[0][0], acc[(I2)+1][0]);                  \
    acc[(I2)+1][1] = MFMA16(aC, bfr[1][0], acc[(I2)+1][1]);                  \
    acc[(I2)+1][2] = MFMA16(aC, bfr[2][0], acc[(I2)+1][2]);                  \
    acc[(I2)+1][3] = MFMA16(aC, bfr[3][0], acc[(I2)+1][3]);                  \
    acc[(I2)+1][0] = MFMA16(aD, bfr[0][1], acc[(I2)+1][0]);                  \
    acc[(I2)+1][1] = MFMA16(aD, bfr[1][1], acc[(I2)+1][1]);                  \
    acc[(I2)+1][2] = MFMA16(aD, bfr[2][1], acc[(I2)+1][2]);                  \
    acc[(I2)+1][3] = MFMA16(aD, bfr[3][1], acc[(I2)+1][3]);                  \
    __builtin_amdgcn_s_setprio(0);                                           \
    VM_STMT;                                                                 \
    CFENCE; RAW_BAR; CFENCE; } while (0)

    // prologue: tile 0 -> buf 0, full drain (only place that drains at issue)
    STAGE_A(0, 0);
    STAGE_B(0, 0);
    VM0;
    __syncthreads();

#pragma unroll 2
    for (int t = 0; t < 16; ++t) {
        const int cur = t & 1, nxt = cur ^ 1;
        const int k0 = t * 64;
        const bool pre = (t < 15);
        const __bf16* Ac = &As[cur][0];
        const __bf16* Bc = &Bs[cur][0];

        bf16x8 bfr[4][2];
        // ---- phase 0: stage A(t+1); read all B-frags + A quad 0; MFMA q0
        if (pre) STAGE_A(nxt, k0 + 64);
#pragma unroll
        for (int j = 0; j < 4; ++j) {
            bfr[j][0] = *(const bf16x8*)&Bc[boff + j * 1024 + s0];
            bfr[j][1] = *(const bf16x8*)&Bc[boff + j * 1024 + s1];
        }
        PHASE(0, (void)0, (void)0);
        // ---- phase 1: stage B(t+1); MFMA q1
        PHASE(2, if (pre) STAGE_B(nxt, k0 + 64), (void)0);
        // ---- phase 2: MFMA q2
        PHASE(4, (void)0, (void)0);
        // ---- phase 3: MFMA q3; counted wait (loads are 2-3 phases old)
        PHASE(6, (void)0, VM0);
    }

    // ---- epilogue: RoPE (+Q scale) and write to Q/K/V (z uniform per block)
    const int z = n0 >> 10;
    __bf16* Cz = (z == 0) ? Qb : (z == 1) ? Kb : Vb;
    const int ncol = n0 & 1023;
#pragma unroll
    for (int i = 0; i < 8; ++i) {
#pragma unroll
        for (int r = 0; r < 4; ++r) {
            int row  = m0 + wr * 128 + i * 16 + hi * 4 + r;
            int tpos = row & (SEQ - 1);
            if (z <= 1) {
#pragma unroll
                for (int j = 0; j < 2; ++j) {
                    int dd = j * 16 + frow;
                    float c = ct[tpos * 32 + dd];
                    float s = st[tpos * 32 + dd];
                    float v0 = acc[i][j][r], v1 = acc[i][j + 2][r];
                    float n0v = v0 * c - v1 * s;
                    float n1v = v1 * c + v0 * s;
                    if (z == 0) { n0v *= 0.125f; n1v *= 0.125f; }
                    acc[i][j][r] = n0v; acc[i][j + 2][r] = n1v;
                }
            }
#pragma unroll
            for (int j = 0; j < 4; ++j) {
                int col = ncol + wc * 64 + j * 16 + frow;
                Cz[(size_t)row * DMODEL + col] = (__bf16)acc[i][j][r];
            }
        }
    }
#undef PHASE
#undef STAGE_A
#undef STAGE_B
}

// ---------------------------------------------------------------------------
// Round-0 BK=128 2-barrier MFMA GEMM body (verified) — used for out-proj.
// C[m][n] = sum_k A[m][k] * B[n][k]. 4 x 32-halves, XOR chunk swizzle.
// ---------------------------------------------------------------------------
template<int TM, int TN>
__device__ __forceinline__ void gemm_mfma_body(
    const __bf16* __restrict__ A, const __bf16* __restrict__ B,
    void* __restrict__ Cout, const float* __restrict__ bias,
    const float* __restrict__ ct, const float* __restrict__ st,
    int mode, int N, int K, int m0, int n0)
{
    constexpr bool SQ = (TN == 128);          // 2x2 wave layout
    constexpr int NI = SQ ? 4 : (TM / 64);    // 16-row i-tiles per wave
    constexpr int NAC = TM / 64;              // A staging calls per wave/half
    constexpr int NBC = TN / 64;              // B staging calls per wave/half
    __shared__ __bf16 As[4][TM * 32];
    __shared__ __bf16 Bs[4][TN * 32];

    const int tid  = threadIdx.x;
    const int lane = tid & 63;
    const int wv   = tid >> 6;
    const int wrow = SQ ? (wv >> 1) * 64 : wv * (TM / 4);
    const int wcol = SQ ? (wv & 1) * 64 : 0;

    const int srow = lane >> 2;
    const int schk = (lane & 3) ^ ((lane >> 3) & 3);
    const int arbase = wv * (TM / 4);
    const int brbase = wv * (TN / 4);

    const __bf16* gA0 = A + (size_t)(m0 + arbase + srow) * K + 8 * schk;
    const __bf16* gA1 = gA0 + (size_t)16 * K;
    const __bf16* gB0 = B + (size_t)(n0 + brbase + srow) * K + 8 * schk;
    const __bf16* gB1 = gB0 + (size_t)16 * K;

    const int frow = lane & 15;
    const int fsw  = 8 * ((lane >> 4) ^ ((frow >> 1) & 3));

    f32x4 acc[NI][4];
#pragma unroll
    for (int i = 0; i < NI; ++i)
#pragma unroll
        for (int j = 0; j < 4; ++j) {
            acc[i][j][0] = 0.f; acc[i][j][1] = 0.f;
            acc[i][j][2] = 0.f; acc[i][j][3] = 0.f;
        }

    for (int k0 = 0; k0 < K; k0 += 128) {
        __syncthreads();                 // prior iter's LDS reads complete
#pragma unroll
        for (int h = 0; h < 4; ++h) {
            async_load16(gA0 + k0 + 32 * h, As[h] + arbase * 32);
            if (NAC == 2)
                async_load16(gA1 + k0 + 32 * h, As[h] + (arbase + 16) * 32);
            async_load16(gB0 + k0 + 32 * h, Bs[h] + brbase * 32);
            if (NBC == 2)
                async_load16(gB1 + k0 + 32 * h, Bs[h] + (brbase + 16) * 32);
        }
        __syncthreads();                 // drains vmcnt: staging visible

#pragma unroll
        for (int h = 0; h < 4; ++h) {
            bf16x8 afr[NI], bfr[4];
#pragma unroll
            for (int i = 0; i < NI; ++i)
                afr[i] = *(const bf16x8*)(As[h] + (wrow + 16 * i + frow) * 32 + fsw);
#pragma unroll
            for (int j = 0; j < 4; ++j)
                bfr[j] = *(const bf16x8*)(Bs[h] + (wcol + 16 * j + frow) * 32 + fsw);
#pragma unroll
            for (int i = 0; i < NI; ++i)
#pragma unroll
                for (int j = 0; j < 4; ++j)
                    acc[i][j] = __builtin_amdgcn_mfma_f32_16x16x32_bf16(
                        afr[i], bfr[j], acc[i][j], 0, 0, 0);
        }
    }

#pragma unroll
    for (int i = 0; i < NI; ++i) {
#pragma unroll
        for (int r = 0; r < 4; ++r) {
            int row = m0 + wrow + i * 16 + (lane >> 4) * 4 + r;
            if (mode <= 1) {
                int t = row & (SEQ - 1);
#pragma unroll
                for (int j = 0; j < 2; ++j) {
                    int dd = j * 16 + (lane & 15);
                    float c = ct[t * 32 + dd];
                    float s = st[t * 32 + dd];
                    float v0 = acc[i][j][r], v1 = acc[i][j + 2][r];
                    float n0v = v0 * c - v1 * s;
                    float n1v = v1 * c + v0 * s;
                    if (mode == 0) { n0v *= 0.125f; n1v *= 0.125f; }
                    acc[i][j][r] = n0v; acc[i][j + 2][r] = n1v;
                }
            }
#pragma unroll
            for (int j = 0; j < 4; ++j) {
                int col = n0 + wcol + j * 16 + (lane & 15);
                float v = acc[i][j][r];
                if (mode == 3)
                    ((float*)Cout)[(size_t)row * N + col] = v + bias[col];
                else
                    ((__bf16*)Cout)[(size_t)row * N + col] = (__bf16)v;
            }
        }
    }
}

// XCD-locality swizzle (verified r7/r8)
template<int GX, int GY>
__device__ __forceinline__ void xcd_swizzle(int& xb, int& yb)
{
    int id = blockIdx.x + GX * blockIdx.y;
    int q  = id & 7;
    int s  = id >> 3;
    xb = s % GX;
    yb = (GY / 8) * q + s / GX;
}

__global__ __launch_bounds__(256) void gemm_out_bf(
    const __bf16* __restrict__ Abf, const __bf16* __restrict__ Wo,
    const float* __restrict__ bias, float* __restrict__ out)
{
    int xb, yb;
    xcd_swizzle<16, 64>(xb, yb);
    gemm_mfma_body<64, 64>(Abf, Wo, out, bias, nullptr, nullptr, 3,
                           DMODEL, DMODEL, yb * 64, xb * 64);
}

// ---------------------------------------------------------------------------
// MFMA sliding-window attention (verified rounds 3-8). One 256-thread block
// per (b, h, 64 q-rows); wave w owns q-rows 16w..16w+15.
// ---------------------------------------------------------------------------
#define QTILE 64
#define KPAD  72    // Ks row (bf16): 36 words/row -> 8 distinct bank offsets
#define VPAD  216   // Vt row: 108 words -> 8 distinct offsets
#define PPAD  168   // Ps row: 84 words -> 8 distinct offsets

__global__ __launch_bounds__(256) void attn_mfma(
    const __bf16* __restrict__ Qb, const __bf16* __restrict__ Kb,
    const __bf16* __restrict__ Vb, __bf16* __restrict__ Abf)
{
    __shared__ __bf16 KsPs[192 * KPAD];  // 27648 B; Ks, then reused as Ps
    __shared__ __bf16 Vt[64 * VPAD];     // 27648 B  (total 55296 B)

    const int tid  = threadIdx.x;
    const int lane = tid & 63;
    const int wv   = tid >> 6;
    const int q0   = blockIdx.x * QTILE;
    const int h    = blockIdx.y;
    const int b    = blockIdx.z;
    const int jbase = q0 - 128;
    const size_t hoff = (size_t)h * HDIM;
    const int nloc  = lane & 15;
    const int mbase = (lane >> 4) * 4;
    const int fk    = (lane >> 4) * 8;

    const __bf16* Kg = Kb + (size_t)(b * SEQ) * DMODEL + hoff;
    const __bf16* Vg = Vb + (size_t)(b * SEQ) * DMODEL + hoff;

    // ---- stage Ks (natural) + Vt (transposed)
#pragma unroll
    for (int it = 0; it < 6; ++it) {
        int idx = tid + it * 256;          // 0..1535
        int jt = idx >> 3;                 // 0..191
        int dq = (idx & 7) * 8;
        int jg = jbase + jt;
        int jc = jg < 0 ? 0 : jg;          // clamp; masked via p=0 later
        bf16x8 kv = *(const bf16x8*)(Kg + (size_t)jc * DMODEL + dq);
        bf16x8 vv = *(const bf16x8*)(Vg + (size_t)jc * DMODEL + dq);
        *(bf16x8*)(KsPs + jt * KPAD + dq) = kv;
#pragma unroll
        for (int e = 0; e < 8; ++e) Vt[(dq + e) * VPAD + jt] = vv[e];
    }
    // zero Vt cols [192,208) (read by PV k-steps; must not be garbage)
#pragma unroll
    for (int it = 0; it < 4; ++it) {
        int idx = tid + it * 256;          // 0..1023
        int d = idx >> 4, c = idx & 15;
        Vt[d * VPAD + 192 + c] = (__bf16)0.0f;
    }
    __syncthreads();

    // ---- Q A-frags direct from global
    const __bf16* Qg = Qb + (size_t)(b * SEQ + q0 + 16 * wv + nloc) * DMODEL + hoff + fk;
    bf16x8 qfr0 = *(const bf16x8*)(Qg);
    bf16x8 qfr1 = *(const bf16x8*)(Qg + 32);

    // ---- S = Q K^T over 9 column tiles
    f32x4 s[9];
#pragma unroll
    for (int c = 0; c < 9; ++c) {
        const __bf16* kp = KsPs + (size_t)(16 * (wv + c) + nloc) * KPAD + fk;
        bf16x8 k0 = *(const bf16x8*)kp;
        bf16x8 k1 = *(const bf16x8*)(kp + 32);
        f32x4 z; z[0] = 0.f; z[1] = 0.f; z[2] = 0.f; z[3] = 0.f;
        z = __builtin_amdgcn_mfma_f32_16x16x32_bf16(qfr0, k0, z, 0, 0, 0);
        z = __builtin_amdgcn_mfma_f32_16x16x32_bf16(qfr1, k1, z, 0, 0, 0);
        s[c] = z;
    }
    __syncthreads();   // all waves done reading Ks; safe to alias with Ps

    // ---- mask + softmax (registers only); write normalized P (bf16)
    float inv_row[4];
#pragma unroll
    for (int r = 0; r < 4; ++r) {
        int rl = 16 * wv + mbase + r;
        float mx = -INFINITY;
#pragma unroll
        for (int c = 0; c < 9; ++c) {
            int jt = 16 * (wv + c) + nloc;
            bool valid = (jt >= rl + 1) && (jt <= rl + 128) && (jbase + jt >= 0);
            float sv = valid ? s[c][r] : -INFINITY;
            s[c][r] = sv;
            mx = fmaxf(mx, sv);
        }
#pragma unroll
        for (int off = 8; off; off >>= 1) mx = fmaxf(mx, __shfl_xor(mx, off));
        float sum = 0.f;
#pragma unroll
        for (int c = 0; c < 9; ++c) {
            float p = __expf(s[c][r] - mx);
            s[c][r] = p;
            sum += p;
        }
#pragma unroll
        for (int off = 8; off; off >>= 1) sum += __shfl_xor(sum, off);
        inv_row[r] = 1.0f / sum;
    }

    __bf16* myP = KsPs + (size_t)wv * 16 * PPAD;
#pragma unroll
    for (int c = 0; c < 9; ++c)
#pragma unroll
        for (int r = 0; r < 4; ++r)
            myP[(mbase + r) * PPAD + 16 * c + nloc] = (__bf16)(s[c][r] * inv_row[r]);
#pragma unroll
    for (int r = 0; r < 4; ++r)       // zero P cols [144,160)
        myP[(mbase + r) * PPAD + 144 + nloc] = (__bf16)0.0f;

    asm volatile("" ::: "memory");
    __builtin_amdgcn_s_waitcnt(0);    // wave-local LDS write->read ordering

    // ---- O = P V  (5 k-steps of 32 keys, 4 d-tiles)
    f32x4 o[4];
#pragma unroll
    for (int j = 0; j < 4; ++j) { o[j][0] = 0.f; o[j][1] = 0.f; o[j][2] = 0.f; o[j][3] = 0.f; }
#pragma unroll
    for (int stp = 0; stp < 5; ++stp) {
        bf16x8 pf = *(const bf16x8*)(myP + nloc * PPAD + 32 * stp + fk);
#pragma unroll
        for (int j = 0; j < 4; ++j) {
            bf16x8 vf = *(const bf16x8*)(Vt + (size_t)(16 * j + nloc) * VPAD
                                         + 16 * wv + 32 * stp + fk);
            o[j] = __builtin_amdgcn_mfma_f32_16x16x32_bf16(pf, vf, o[j], 0, 0, 0);
        }
    }

    // ---- epilogue: C-layout -> global bf16
    __bf16* Og = Abf + (size_t)(b * SEQ + q0 + 16 * wv) * DMODEL + hoff;
#pragma unroll
    for (int j = 0; j < 4; ++j)
#pragma unroll
        for (int r = 0; r < 4; ++r)
            Og[(size_t)(mbase + r) * DMODEL + 16 * j + nloc] = (__bf16)o[j][r];
}

// ---------------------------------------------------------------------------
extern "C" void kernel_launch(void* const* d_in, const int* in_sizes, int n_in,
                              void* d_out, int out_size, void* d_ws, size_t ws_size,
                              hipStream_t stream)
{
    const float* X  = (const float*)d_in[0];
    const float* Wq = (const float*)d_in[1];
    const float* Wk = (const float*)d_in[2];
    const float* Wv = (const float*)d_in[3];
    const float* Wo = (const float*)d_in[4];
    const float* bo = (const float*)d_in[5];
    float* out = (float*)d_out;

    const size_t MB = 1ull << 20;
    __bf16* Xbf = (__bf16*)d_ws;                        // 8 MB; reused as Abf
    __bf16* Wbf = (__bf16*)((char*)d_ws + 8 * MB);      // 8 MB (Wq|Wk|Wv|Wo)
    __bf16* Qb  = (__bf16*)((char*)d_ws + 16 * MB);     // 8 MB
    __bf16* Kb  = (__bf16*)((char*)d_ws + 24 * MB);     // 8 MB
    __bf16* Vb  = (__bf16*)((char*)d_ws + 32 * MB);     // 8 MB
    float*  ctab = (float*)((char*)d_ws + 40 * MB);     // 256 KB
    float*  stab = (float*)((char*)d_ws + 41 * MB);     // 256 KB
    __bf16* Abf = Xbf;   // X dead after QKV projection

    // 1. fp32 -> bf16 conversion + RoPE table (fused)
    {
        int total = (ROWS * DMODEL + 4 * DMODEL * DMODEL) / 4 + SEQ * 32;
        convert_bf16<<<(total + 255) / 256, 256, 0, stream>>>(
            X, Wq, Wk, Wv, Wo, Xbf, Wbf, ctab, stab);
    }
    // 2. Fused QKV projection (N=3072) with RoPE (+Q scale), 8-phase 256^2
    {
        dim3 grid(12, 16, 1);
        gemm_qkv_8ph<<<grid, 512, 0, stream>>>(Xbf, Wbf, Qb, Kb, Vb, ctab, stab);
    }
    // 3. MFMA sliding-window attention -> bf16
    {
        dim3 grid(SEQ / QTILE, NHEADS, BATCH);
        attn_mfma<<<grid, 256, 0, stream>>>(Qb, Kb, Vb, Abf);
    }
    // 4. Output projection + bias (fp32 out); 64x64 tiles (round-0 verified)
    {
        dim3 grid(DMODEL / 64, ROWS / 64, 1);
        gemm_out_bf<<<grid, 256, 0, stream>>>(Abf, Wbf + 3ull * DMODEL * DMODEL, bo, out);
    }
}